// Round 1
// baseline (344.798 us; speedup 1.0000x reference)
//
#include <hip/hip_runtime.h>

// MultiRelGraphTransformer on MI355X — round 7.
// vs r6: (a) k_spmm gathers are single 16B uint4 loads (was 2x ushort4),
// (b) srcs[] stores pre-scaled BYTE offsets (src*256) so gather addr is one
// 32-bit v_add vs a 64-bit mul chain, (c) packed f32x2 accumulate (v_pk_add_f32),
// (d) src-index int4 prefetch + all-relation deg/first-idx issued upfront,
// (e) k_gemm_ln M-tile 64->128 rows/block (Wt staging amortized 2x, ds_read/MFMA halved).

#define NNODES 20000
#define NB     4
#define BROWS  (NB * NNODES)   // 80000
#define DN     64
#define DM     128
#define NE     160000
#define CAP    64              // bucket capacity per (relation,dst); Poisson(8)
#define LN_EPS 1e-5f
#define KE     448             // 384 spmm cols + 64 ext cols
#define LDW    88              // LDS row stride in ushorts: 44 dw -> 2-way (free)

typedef __attribute__((ext_vector_type(8))) short bf16x8;
typedef __attribute__((ext_vector_type(4))) float f32x4;
typedef __attribute__((ext_vector_type(2))) float f32x2;
typedef __attribute__((ext_vector_type(8))) unsigned short u16x8;

__device__ inline float bf2f(unsigned short u) {
    union { unsigned int i; float f; } x; x.i = ((unsigned int)u) << 16; return x.f;
}
__device__ inline unsigned short f2bf(float f) {
    union { float f; unsigned int i; } x; x.f = f;
    unsigned int r = x.i + 0x7FFFu + ((x.i >> 16) & 1u);
    return (unsigned short)(r >> 16);
}
// unpack one dword (2 bf16) into a packed float2 {lo, hi}
__device__ inline f32x2 bfpair(unsigned int w) {
    union { unsigned int u; float f; } lo, hi;
    lo.u = w << 16; hi.u = w & 0xffff0000u;
    return (f32x2){lo.f, hi.f};
}

// ---------- K1: counting-sort into fixed buckets (cursor = true degree) ----------
// srcs[] now stores BYTE offsets into an HB batch plane: src * DM * 2 = src*256.
__global__ void k_scatter(const int* __restrict__ ei0, const int* __restrict__ ei1,
                          const int* __restrict__ ei2, int* __restrict__ cursor,
                          int* __restrict__ srcs, int* __restrict__ eids) {
    int tid = blockIdx.x * blockDim.x + threadIdx.x;
    if (tid >= 3 * NE) return;
    int r = tid / NE, e = tid - r * NE;
    const int* ei = (r == 0) ? ei0 : ((r == 1) ? ei1 : ei2);
    int src = ei[e], dst = ei[NE + e];
    int p = atomicAdd(&cursor[r * NNODES + dst], 1);
    if (p < CAP) {
        srcs[(r * NNODES + dst) * CAP + p] = src << 8;   // byte offset
        if (r < 2) eids[(r * NNODES + dst) * CAP + p] = e;
    }
}

// ---------- K2: S[r][n][16] = sum of ea_r over incoming edges (bucket walk) ----------
__global__ __launch_bounds__(256) void k_sgather(const int* __restrict__ deg,
                                                 const int* __restrict__ eids,
                                                 const float* __restrict__ ea0,
                                                 const float* __restrict__ ea1,
                                                 float* __restrict__ S) {
    int task = blockIdx.x * 4 + (threadIdx.x >> 6);   // 0 .. 2*NNODES-1
    int r = task / NNODES;
    const float* ea = r ? ea1 : ea0;
    int lane = threadIdx.x & 63;
    int k = lane & 15, sub = lane >> 4;
    int dg = deg[task]; if (dg > CAP) dg = CAP;
    const int* bk = eids + (size_t)task * CAP;
    float acc = 0.f;
    for (int j = sub; j < dg; j += 4) {
        int e = bk[j];
        acc += ea[e * 16 + k];
    }
    acc += __shfl_xor(acc, 16, 64);
    acc += __shfl_xor(acc, 32, 64);
    if (lane < 16) S[(size_t)task * 16 + k] = acc;
}

// ---------- K3: build Wt[2][128][448] (transposed node_W + ext rows) and Wp[128][64] ----------
__global__ __launch_bounds__(256) void k_wprep(const float* __restrict__ nW,
                                               const float* __restrict__ nb,
                                               const float* __restrict__ eW,
                                               const float* __restrict__ eb,
                                               const float* __restrict__ inW,
                                               unsigned short* __restrict__ Wt,
                                               unsigned short* __restrict__ Wp) {
    int lin = blockIdx.x * 256 + threadIdx.x;    // 2*128*448 + 128*64 = 122880
    if (lin < 2 * 128 * KE) {
        int l = lin / (128 * KE);
        int rem = lin - l * 128 * KE;
        int n = rem / KE, k = rem - n * KE;
        float v;
        if (k < 384) {
            int r = k >> 7, kk = k & 127;
            v = nW[(((size_t)(l * 3 + r) * 128) + kk) * 128 + n];
        } else {
            int e = k - 384;
            if (e < 3) {
                v = nb[(l * 3 + e) * DM + n];
                if (e < 2) v += eb[(l * 2 + e) * DM + n];
            } else if (e < 35) {
                int r2 = (e - 3) >> 4, j = (e - 3) & 15;
                v = eW[((size_t)((l * 2 + r2) * 16 + j)) * DM + n];
            } else v = 0.f;
        }
        Wt[lin] = f2bf(v);
    } else {
        int i = lin - 2 * 128 * KE;
        int n = i >> 6, k = i & 63;
        Wp[n * 64 + k] = f2bf(inW[(size_t)k * DM + n]);
    }
}

// ---------- K4: input projection HB = bf16(node_feat @ in_W + in_b), MFMA ----------
__global__ __launch_bounds__(256) void k_proj(const float* __restrict__ X,
                                              const unsigned short* __restrict__ Wp,  // [128][64]
                                              const float* __restrict__ bias,
                                              unsigned short* __restrict__ HB) {
    __shared__ __align__(16) unsigned short As[64][LDW];
    __shared__ __align__(16) unsigned short Bs[128][LDW];
    int t = threadIdx.x;
    int m0 = blockIdx.x * 64;
#pragma unroll
    for (int i = 0; i < 4; ++i) {
        int lin = t + 256 * i;                 // 0..1023 (64 rows x 16 float4-segs)
        int row = lin >> 4, seg = lin & 15;
        float4 v = *(const float4*)(X + (size_t)(m0 + row) * DN + seg * 4);
        ushort4 h; h.x = f2bf(v.x); h.y = f2bf(v.y); h.z = f2bf(v.z); h.w = f2bf(v.w);
        *(ushort4*)&As[row][seg * 4] = h;
    }
#pragma unroll
    for (int i = 0; i < 4; ++i) {
        int lin = t + 256 * i;                 // 0..1023 (128 rows x 8 uint4-segs)
        int row = lin >> 3, seg = lin & 7;
        *(uint4*)&Bs[row][seg * 8] = *(const uint4*)(Wp + (size_t)row * 64 + seg * 8);
    }
    __syncthreads();
    int w = t >> 6, lane = t & 63;
    int q = lane >> 4, lm = lane & 15;
    f32x4 acc[8];
#pragma unroll
    for (int ct = 0; ct < 8; ++ct) acc[ct] = (f32x4){0.f, 0.f, 0.f, 0.f};
#pragma unroll
    for (int kt = 0; kt < 2; ++kt) {
        bf16x8 a = *(const bf16x8*)&As[w * 16 + lm][kt * 32 + q * 8];
#pragma unroll
        for (int ct = 0; ct < 8; ++ct) {
            bf16x8 bf = *(const bf16x8*)&Bs[ct * 16 + lm][kt * 32 + q * 8];
            acc[ct] = __builtin_amdgcn_mfma_f32_16x16x32_bf16(a, bf, acc[ct], 0, 0, 0);
        }
    }
#pragma unroll
    for (int reg = 0; reg < 4; ++reg) {
        int row = m0 + w * 16 + q * 4 + reg;
#pragma unroll
        for (int ct = 0; ct < 8; ++ct) {
            int col = ct * 16 + lm;
            HB[(size_t)row * DM + col] = f2bf(acc[ct][reg] + bias[col]);
        }
    }
}

// ---------- gather one relation: sum up to dg rows (byte-offset bucket) ----------
__device__ inline void gather_rel(const char* __restrict__ HbB, unsigned c16,
                                  const int* __restrict__ bk, int dg, int4 s4,
                                  f32x2* a) {
#pragma unroll
    for (int i = 0; i < 4; ++i) a[i] = (f32x2){0.f, 0.f};
    int j = 0;
    while (j + 3 < dg) {
        bool more = (j + 7 < dg);
        int4 nxt = s4;
        if (more) nxt = *(const int4*)(bk + j + 4);     // prefetch next indices
        uint4 u0 = *(const uint4*)(HbB + ((unsigned)s4.x + c16));
        uint4 u1 = *(const uint4*)(HbB + ((unsigned)s4.y + c16));
        uint4 u2 = *(const uint4*)(HbB + ((unsigned)s4.z + c16));
        uint4 u3 = *(const uint4*)(HbB + ((unsigned)s4.w + c16));
        a[0] += bfpair(u0.x) + bfpair(u1.x) + bfpair(u2.x) + bfpair(u3.x);
        a[1] += bfpair(u0.y) + bfpair(u1.y) + bfpair(u2.y) + bfpair(u3.y);
        a[2] += bfpair(u0.z) + bfpair(u1.z) + bfpair(u2.z) + bfpair(u3.z);
        a[3] += bfpair(u0.w) + bfpair(u1.w) + bfpair(u2.w) + bfpair(u3.w);
        j += 4;
        s4 = nxt;
    }
    for (; j < dg; ++j) {
        uint4 u = *(const uint4*)(HbB + ((unsigned)bk[j] + c16));
        a[0] += bfpair(u.x); a[1] += bfpair(u.y);
        a[2] += bfpair(u.z); a[3] += bfpair(u.w);
    }
}

// ---------- K5: SpMM + ext-col write ----------
// Block = 16 nodes x 1 batch (XCD affinity). 16 lanes x one dwordx4 per row.
__global__ __launch_bounds__(256) void k_spmm(const unsigned short* __restrict__ HB,
                                              const int* __restrict__ deg,
                                              const int* __restrict__ srcs,
                                              const float* __restrict__ S,
                                              unsigned short* __restrict__ G) {
    int blk = blockIdx.x;                      // 5000
    int s = blk & 7;
    int bb = s >> 1;                           // xcd -> batch
    int idx = ((blk >> 3) << 1) + (s & 1);     // [0,1250)
    int n0 = idx * 16;
    int g = threadIdx.x >> 4, lane = threadIdx.x & 15;
    int n = n0 + g;
    unsigned c16 = (unsigned)lane * 16;        // byte offset within row
    const char* HbB = (const char*)HB + (size_t)bb * NNODES * DM * 2;
    size_t rowbase = ((size_t)(bb * NNODES + n)) * KE;

    // issue all degree + first-index loads upfront
    int dt0 = deg[n], dt1 = deg[NNODES + n], dt2 = deg[2 * NNODES + n];
    const int* bk0 = srcs + (size_t)n * CAP;
    const int* bk1 = bk0 + (size_t)NNODES * CAP;
    const int* bk2 = bk1 + (size_t)NNODES * CAP;
    int4 f0 = *(const int4*)bk0;
    int4 f1 = *(const int4*)bk1;
    int4 f2 = *(const int4*)bk2;

    f32x2 a[4];
    u16x8 o;

    gather_rel(HbB, c16, bk0, dt0 > CAP ? CAP : dt0, f0, a);
#pragma unroll
    for (int i = 0; i < 4; ++i) { o[2 * i] = f2bf(a[i].x); o[2 * i + 1] = f2bf(a[i].y); }
    *(u16x8*)(G + rowbase + 0 * 128 + lane * 8) = o;

    gather_rel(HbB, c16, bk1, dt1 > CAP ? CAP : dt1, f1, a);
#pragma unroll
    for (int i = 0; i < 4; ++i) { o[2 * i] = f2bf(a[i].x); o[2 * i + 1] = f2bf(a[i].y); }
    *(u16x8*)(G + rowbase + 1 * 128 + lane * 8) = o;

    gather_rel(HbB, c16, bk2, dt2 > CAP ? CAP : dt2, f2, a);
#pragma unroll
    for (int i = 0; i < 4; ++i) { o[2 * i] = f2bf(a[i].x); o[2 * i + 1] = f2bf(a[i].y); }
    *(u16x8*)(G + rowbase + 2 * 128 + lane * 8) = o;

    // ext cols: lanes 0..7 write 8 bf16 each -> kk = lane*8+j
    if (lane < 8) {
        int dt[3] = {dt0, dt1, dt2};
        u16x8 e;
#pragma unroll
        for (int j = 0; j < 8; ++j) {
            int kk = lane * 8 + j;
            float v;
            if (kk < 3)       v = (float)dt[kk];
            else if (kk < 19) v = S[((size_t)(0 * NNODES + n)) * 16 + (kk - 3)];
            else if (kk < 35) v = S[((size_t)(1 * NNODES + n)) * 16 + (kk - 19)];
            else              v = 0.f;
            e[j] = f2bf(v);
        }
        *(u16x8*)(G + rowbase + 384 + lane * 8) = e;
    }
}

// ---------- K6: bf16 MFMA GEMM [128x448]@[448x128] + residual + ReLU + LN ----------
// M-tile 128: Wt staging amortized over 2x rows, ds_read per MFMA halved.
__global__ __launch_bounds__(256) void k_gemm_ln(const unsigned short* __restrict__ G,   // [BROWS][448]
                                                 const unsigned short* __restrict__ Wt,  // [128][448]
                                                 unsigned short* HB,
                                                 const float* __restrict__ lng,
                                                 const float* __restrict__ lnb,
                                                 float* __restrict__ out, int write_f32) {
    __shared__ __align__(16) unsigned short Gs[128][LDW];
    __shared__ __align__(16) unsigned short Ws[128][LDW];
    int t = threadIdx.x;
    int m0 = blockIdx.x * 128;
    int w = t >> 6, lane = t & 63;
    int q = lane >> 4, lm = lane & 15;

    f32x4 acc[2][8];
#pragma unroll
    for (int af = 0; af < 2; ++af)
#pragma unroll
        for (int ct = 0; ct < 8; ++ct) acc[af][ct] = (f32x4){0.f, 0.f, 0.f, 0.f};

    for (int kc = 0; kc < 7; ++kc) {
        // stage G chunk: 128 rows x 64 k (1024 uint4)
#pragma unroll
        for (int i = 0; i < 4; ++i) {
            int lin = t + 256 * i;
            int row = lin >> 3, seg = lin & 7;
            *(uint4*)&Gs[row][seg * 8] =
                *(const uint4*)(G + (size_t)(m0 + row) * KE + kc * 64 + seg * 8);
        }
        // stage Wt chunk: 128 rows x 64 k (1024 uint4)
#pragma unroll
        for (int i = 0; i < 4; ++i) {
            int lin = t + 256 * i;
            int row = lin >> 3, seg = lin & 7;
            *(uint4*)&Ws[row][seg * 8] =
                *(const uint4*)(Wt + (size_t)row * KE + kc * 64 + seg * 8);
        }
        __syncthreads();
#pragma unroll
        for (int kt = 0; kt < 2; ++kt) {
            bf16x8 a0 = *(const bf16x8*)&Gs[w * 16 + lm][kt * 32 + q * 8];
            bf16x8 a1 = *(const bf16x8*)&Gs[64 + w * 16 + lm][kt * 32 + q * 8];
#pragma unroll
            for (int ct = 0; ct < 8; ++ct) {
                bf16x8 bf = *(const bf16x8*)&Ws[ct * 16 + lm][kt * 32 + q * 8];
                acc[0][ct] = __builtin_amdgcn_mfma_f32_16x16x32_bf16(a0, bf, acc[0][ct], 0, 0, 0);
                acc[1][ct] = __builtin_amdgcn_mfma_f32_16x16x32_bf16(a1, bf, acc[1][ct], 0, 0, 0);
            }
        }
        __syncthreads();
    }

    float gc[8], bc[8];
#pragma unroll
    for (int ct = 0; ct < 8; ++ct) {
        int col = ct * 16 + lm;
        gc[ct] = lng[col]; bc[ct] = lnb[col];
    }
#pragma unroll
    for (int af = 0; af < 2; ++af) {
#pragma unroll
        for (int reg = 0; reg < 4; ++reg) {
            size_t row = (size_t)m0 + af * 64 + w * 16 + q * 4 + reg;
            float xv[8];
            float s1 = 0.f, s2 = 0.f;
#pragma unroll
            for (int ct = 0; ct < 8; ++ct) {
                int col = ct * 16 + lm;
                float h = bf2f(HB[row * DM + col]);
                float v = h + fmaxf(acc[af][ct][reg], 0.f);
                xv[ct] = v; s1 += v; s2 += v * v;
            }
#pragma unroll
            for (int m = 1; m <= 8; m <<= 1) {
                s1 += __shfl_xor(s1, m, 64);
                s2 += __shfl_xor(s2, m, 64);
            }
            float mu  = s1 * (1.f / 128.f);
            float var = s2 * (1.f / 128.f) - mu * mu;
            float inv = rsqrtf(var + LN_EPS);
            if (write_f32) {
#pragma unroll
                for (int ct = 0; ct < 8; ++ct) {
                    int col = ct * 16 + lm;
                    out[row * DM + col] = (xv[ct] - mu) * inv * gc[ct] + bc[ct];
                }
            } else {
#pragma unroll
                for (int ct = 0; ct < 8; ++ct) {
                    int col = ct * 16 + lm;
                    HB[row * DM + col] = f2bf((xv[ct] - mu) * inv * gc[ct] + bc[ct]);
                }
            }
        }
    }
}

extern "C" void kernel_launch(void* const* d_in, const int* in_sizes, int n_in,
                              void* d_out, int out_size, void* d_ws, size_t ws_size,
                              hipStream_t stream) {
    const float* node_feat = (const float*)d_in[0];
    const float* in_W   = (const float*)d_in[1];
    const float* in_b   = (const float*)d_in[2];
    const float* node_W = (const float*)d_in[3];   // [2][3][128][128]
    const float* node_b = (const float*)d_in[4];   // [2][3][128]
    const float* edge_W = (const float*)d_in[5];   // [2][2][16][128]
    const float* edge_b = (const float*)d_in[6];   // [2][2][128]
    const float* ln_g   = (const float*)d_in[7];   // [2][128]
    const float* ln_b   = (const float*)d_in[8];   // [2][128]
    const float* ea0    = (const float*)d_in[9];
    const float* ea1    = (const float*)d_in[10];
    const int*   ei0    = (const int*)d_in[11];
    const int*   ei1    = (const int*)d_in[12];
    const int*   ei2    = (const int*)d_in[13];
    float* out = (float*)d_out;

    char* ws = (char*)d_ws;
    size_t off = 0;
    auto alloc = [&](size_t bytes) -> void* {
        void* p = ws + off;
        off = (off + bytes + 255) & ~(size_t)255;
        return p;
    };
    unsigned short* HB     = (unsigned short*)alloc((size_t)BROWS * DM * 2);   // 20.5 MB
    unsigned short* G      = (unsigned short*)alloc((size_t)BROWS * KE * 2);   // 71.7 MB
    int*            cursor = (int*)alloc((size_t)3 * NNODES * 4);              // zeroed
    float*          S      = (float*)alloc((size_t)2 * NNODES * 16 * 4);
    int*            srcs   = (int*)alloc((size_t)3 * NNODES * CAP * 4);        // 15.4 MB
    int*            eids   = (int*)alloc((size_t)2 * NNODES * CAP * 4);        // 10.2 MB
    unsigned short* Wt     = (unsigned short*)alloc((size_t)2 * 128 * KE * 2);
    unsigned short* Wp     = (unsigned short*)alloc((size_t)128 * 64 * 2);

    hipMemsetAsync(cursor, 0, (size_t)3 * NNODES * 4, stream);

    k_scatter<<<(3 * NE + 255) / 256, 256, 0, stream>>>(ei0, ei1, ei2, cursor, srcs, eids);
    k_sgather<<<(2 * NNODES) / 4, 256, 0, stream>>>(cursor, eids, ea0, ea1, S);
    k_wprep<<<480, 256, 0, stream>>>(node_W, node_b, edge_W, edge_b, in_W, Wt, Wp);
    k_proj<<<BROWS / 64, 256, 0, stream>>>(node_feat, Wp, in_b, HB);

    for (int l = 0; l < 2; ++l) {
        k_spmm<<<5000, 256, 0, stream>>>(HB, cursor, srcs, S, G);
        k_gemm_ln<<<BROWS / 128, 256, 0, stream>>>(G, Wt + (size_t)l * 128 * KE, HB,
                                                   ln_g + (size_t)l * DM, ln_b + (size_t)l * DM,
                                                   out, l == 1);
    }
}

// Round 2
// 335.848 us; speedup vs baseline: 1.0266x; 1.0266x over previous
//
#include <hip/hip_runtime.h>

// MultiRelGraphTransformer on MI355X — round 8.
// vs r7: (a) k_gemm_ln REVERTED to r6 64-row M-tile (128-row cost ~+9µs/dispatch:
// 45KB LDS -> 3 blocks/CU + 625-block imbalance), (b) k_spmm gather is a depth-2
// software pipeline: burst k+1's 4 uint4 loads issue before burst k is consumed
// (8 gathers + 1 idx in flight vs 4, attacks the ~900cy HBM-miss latency that
// r7's VALU trim couldn't touch), (c) dropped r7's beyond-bucket int4 prefetch
// (it inflated FETCH_SIZE 127->135MB).

#define NNODES 20000
#define NB     4
#define BROWS  (NB * NNODES)   // 80000
#define DN     64
#define DM     128
#define NE     160000
#define CAP    64              // bucket capacity per (relation,dst); Poisson(8)
#define LN_EPS 1e-5f
#define KE     448             // 384 spmm cols + 64 ext cols
#define LDW    88              // LDS row stride in ushorts: 44 dw -> 2-way (free)

typedef __attribute__((ext_vector_type(8))) short bf16x8;
typedef __attribute__((ext_vector_type(4))) float f32x4;
typedef __attribute__((ext_vector_type(2))) float f32x2;
typedef __attribute__((ext_vector_type(8))) unsigned short u16x8;

__device__ inline float bf2f(unsigned short u) {
    union { unsigned int i; float f; } x; x.i = ((unsigned int)u) << 16; return x.f;
}
__device__ inline unsigned short f2bf(float f) {
    union { float f; unsigned int i; } x; x.f = f;
    unsigned int r = x.i + 0x7FFFu + ((x.i >> 16) & 1u);
    return (unsigned short)(r >> 16);
}
// unpack one dword (2 bf16) into a packed float2 {lo, hi}
__device__ inline f32x2 bfpair(unsigned int w) {
    union { unsigned int u; float f; } lo, hi;
    lo.u = w << 16; hi.u = w & 0xffff0000u;
    return (f32x2){lo.f, hi.f};
}

// ---------- K1: counting-sort into fixed buckets (cursor = true degree) ----------
// srcs[] stores BYTE offsets into an HB batch plane: src * DM * 2 = src*256.
__global__ void k_scatter(const int* __restrict__ ei0, const int* __restrict__ ei1,
                          const int* __restrict__ ei2, int* __restrict__ cursor,
                          int* __restrict__ srcs, int* __restrict__ eids) {
    int tid = blockIdx.x * blockDim.x + threadIdx.x;
    if (tid >= 3 * NE) return;
    int r = tid / NE, e = tid - r * NE;
    const int* ei = (r == 0) ? ei0 : ((r == 1) ? ei1 : ei2);
    int src = ei[e], dst = ei[NE + e];
    int p = atomicAdd(&cursor[r * NNODES + dst], 1);
    if (p < CAP) {
        srcs[(r * NNODES + dst) * CAP + p] = src << 8;   // byte offset
        if (r < 2) eids[(r * NNODES + dst) * CAP + p] = e;
    }
}

// ---------- K2: S[r][n][16] = sum of ea_r over incoming edges (bucket walk) ----------
__global__ __launch_bounds__(256) void k_sgather(const int* __restrict__ deg,
                                                 const int* __restrict__ eids,
                                                 const float* __restrict__ ea0,
                                                 const float* __restrict__ ea1,
                                                 float* __restrict__ S) {
    int task = blockIdx.x * 4 + (threadIdx.x >> 6);   // 0 .. 2*NNODES-1
    int r = task / NNODES;
    const float* ea = r ? ea1 : ea0;
    int lane = threadIdx.x & 63;
    int k = lane & 15, sub = lane >> 4;
    int dg = deg[task]; if (dg > CAP) dg = CAP;
    const int* bk = eids + (size_t)task * CAP;
    float acc = 0.f;
    for (int j = sub; j < dg; j += 4) {
        int e = bk[j];
        acc += ea[e * 16 + k];
    }
    acc += __shfl_xor(acc, 16, 64);
    acc += __shfl_xor(acc, 32, 64);
    if (lane < 16) S[(size_t)task * 16 + k] = acc;
}

// ---------- K3: build Wt[2][128][448] (transposed node_W + ext rows) and Wp[128][64] ----------
__global__ __launch_bounds__(256) void k_wprep(const float* __restrict__ nW,
                                               const float* __restrict__ nb,
                                               const float* __restrict__ eW,
                                               const float* __restrict__ eb,
                                               const float* __restrict__ inW,
                                               unsigned short* __restrict__ Wt,
                                               unsigned short* __restrict__ Wp) {
    int lin = blockIdx.x * 256 + threadIdx.x;    // 2*128*448 + 128*64 = 122880
    if (lin < 2 * 128 * KE) {
        int l = lin / (128 * KE);
        int rem = lin - l * 128 * KE;
        int n = rem / KE, k = rem - n * KE;
        float v;
        if (k < 384) {
            int r = k >> 7, kk = k & 127;
            v = nW[(((size_t)(l * 3 + r) * 128) + kk) * 128 + n];
        } else {
            int e = k - 384;
            if (e < 3) {
                v = nb[(l * 3 + e) * DM + n];
                if (e < 2) v += eb[(l * 2 + e) * DM + n];
            } else if (e < 35) {
                int r2 = (e - 3) >> 4, j = (e - 3) & 15;
                v = eW[((size_t)((l * 2 + r2) * 16 + j)) * DM + n];
            } else v = 0.f;
        }
        Wt[lin] = f2bf(v);
    } else {
        int i = lin - 2 * 128 * KE;
        int n = i >> 6, k = i & 63;
        Wp[n * 64 + k] = f2bf(inW[(size_t)k * DM + n]);
    }
}

// ---------- K4: input projection HB = bf16(node_feat @ in_W + in_b), MFMA ----------
__global__ __launch_bounds__(256) void k_proj(const float* __restrict__ X,
                                              const unsigned short* __restrict__ Wp,  // [128][64]
                                              const float* __restrict__ bias,
                                              unsigned short* __restrict__ HB) {
    __shared__ __align__(16) unsigned short As[64][LDW];
    __shared__ __align__(16) unsigned short Bs[128][LDW];
    int t = threadIdx.x;
    int m0 = blockIdx.x * 64;
#pragma unroll
    for (int i = 0; i < 4; ++i) {
        int lin = t + 256 * i;                 // 0..1023 (64 rows x 16 float4-segs)
        int row = lin >> 4, seg = lin & 15;
        float4 v = *(const float4*)(X + (size_t)(m0 + row) * DN + seg * 4);
        ushort4 h; h.x = f2bf(v.x); h.y = f2bf(v.y); h.z = f2bf(v.z); h.w = f2bf(v.w);
        *(ushort4*)&As[row][seg * 4] = h;
    }
#pragma unroll
    for (int i = 0; i < 4; ++i) {
        int lin = t + 256 * i;                 // 0..1023 (128 rows x 8 uint4-segs)
        int row = lin >> 3, seg = lin & 7;
        *(uint4*)&Bs[row][seg * 8] = *(const uint4*)(Wp + (size_t)row * 64 + seg * 8);
    }
    __syncthreads();
    int w = t >> 6, lane = t & 63;
    int q = lane >> 4, lm = lane & 15;
    f32x4 acc[8];
#pragma unroll
    for (int ct = 0; ct < 8; ++ct) acc[ct] = (f32x4){0.f, 0.f, 0.f, 0.f};
#pragma unroll
    for (int kt = 0; kt < 2; ++kt) {
        bf16x8 a = *(const bf16x8*)&As[w * 16 + lm][kt * 32 + q * 8];
#pragma unroll
        for (int ct = 0; ct < 8; ++ct) {
            bf16x8 bf = *(const bf16x8*)&Bs[ct * 16 + lm][kt * 32 + q * 8];
            acc[ct] = __builtin_amdgcn_mfma_f32_16x16x32_bf16(a, bf, acc[ct], 0, 0, 0);
        }
    }
#pragma unroll
    for (int reg = 0; reg < 4; ++reg) {
        int row = m0 + w * 16 + q * 4 + reg;
#pragma unroll
        for (int ct = 0; ct < 8; ++ct) {
            int col = ct * 16 + lm;
            HB[(size_t)row * DM + col] = f2bf(acc[ct][reg] + bias[col]);
        }
    }
}

__device__ inline uint4 ld16(const char* __restrict__ base, unsigned off) {
    return *(const uint4*)(base + off);
}
__device__ inline void acc4(f32x2* a, uint4 p0, uint4 p1, uint4 p2, uint4 p3) {
    a[0] += (bfpair(p0.x) + bfpair(p1.x)) + (bfpair(p2.x) + bfpair(p3.x));
    a[1] += (bfpair(p0.y) + bfpair(p1.y)) + (bfpair(p2.y) + bfpair(p3.y));
    a[2] += (bfpair(p0.z) + bfpair(p1.z)) + (bfpair(p2.z) + bfpair(p3.z));
    a[3] += (bfpair(p0.w) + bfpair(p1.w)) + (bfpair(p2.w) + bfpair(p3.w));
}

// ---------- gather one relation: depth-2 software-pipelined burst loop ----------
__device__ inline void gather_rel(const char* __restrict__ HbB, unsigned c16,
                                  const int* __restrict__ bk, int dg, f32x2* a) {
#pragma unroll
    for (int i = 0; i < 4; ++i) a[i] = (f32x2){0.f, 0.f};
    int nb = dg >> 2;
    int j = nb << 2;
    if (nb > 0) {
        int4 s = *(const int4*)bk;
        uint4 p0 = ld16(HbB, (unsigned)s.x + c16);
        uint4 p1 = ld16(HbB, (unsigned)s.y + c16);
        uint4 p2 = ld16(HbB, (unsigned)s.z + c16);
        uint4 p3 = ld16(HbB, (unsigned)s.w + c16);
        for (int b = 1; b < nb; ++b) {
            int4 s2 = *(const int4*)(bk + (b << 2));
            uint4 q0 = ld16(HbB, (unsigned)s2.x + c16);
            uint4 q1 = ld16(HbB, (unsigned)s2.y + c16);
            uint4 q2 = ld16(HbB, (unsigned)s2.z + c16);
            uint4 q3 = ld16(HbB, (unsigned)s2.w + c16);
            acc4(a, p0, p1, p2, p3);
            p0 = q0; p1 = q1; p2 = q2; p3 = q3;
        }
        acc4(a, p0, p1, p2, p3);
    }
    for (; j < dg; ++j) {
        uint4 u = ld16(HbB, (unsigned)bk[j] + c16);
        a[0] += bfpair(u.x); a[1] += bfpair(u.y);
        a[2] += bfpair(u.z); a[3] += bfpair(u.w);
    }
}

// ---------- K5: SpMM + ext-col write ----------
// Block = 16 nodes x 1 batch (XCD affinity). 16 lanes x one dwordx4 per row.
__global__ __launch_bounds__(256) void k_spmm(const unsigned short* __restrict__ HB,
                                              const int* __restrict__ deg,
                                              const int* __restrict__ srcs,
                                              const float* __restrict__ S,
                                              unsigned short* __restrict__ G) {
    int blk = blockIdx.x;                      // 5000
    int s = blk & 7;
    int bb = s >> 1;                           // xcd -> batch
    int idx = ((blk >> 3) << 1) + (s & 1);     // [0,1250)
    int n0 = idx * 16;
    int g = threadIdx.x >> 4, lane = threadIdx.x & 15;
    int n = n0 + g;
    unsigned c16 = (unsigned)lane * 16;        // byte offset within row
    const char* HbB = (const char*)HB + (size_t)bb * NNODES * DM * 2;
    size_t rowbase = ((size_t)(bb * NNODES + n)) * KE;

    int dt0 = deg[n], dt1 = deg[NNODES + n], dt2 = deg[2 * NNODES + n];
    const int* bk0 = srcs + (size_t)n * CAP;
    const int* bk1 = bk0 + (size_t)NNODES * CAP;
    const int* bk2 = bk1 + (size_t)NNODES * CAP;

    f32x2 a[4];
    u16x8 o;

    gather_rel(HbB, c16, bk0, dt0 > CAP ? CAP : dt0, a);
#pragma unroll
    for (int i = 0; i < 4; ++i) { o[2 * i] = f2bf(a[i].x); o[2 * i + 1] = f2bf(a[i].y); }
    *(u16x8*)(G + rowbase + 0 * 128 + lane * 8) = o;

    gather_rel(HbB, c16, bk1, dt1 > CAP ? CAP : dt1, a);
#pragma unroll
    for (int i = 0; i < 4; ++i) { o[2 * i] = f2bf(a[i].x); o[2 * i + 1] = f2bf(a[i].y); }
    *(u16x8*)(G + rowbase + 1 * 128 + lane * 8) = o;

    gather_rel(HbB, c16, bk2, dt2 > CAP ? CAP : dt2, a);
#pragma unroll
    for (int i = 0; i < 4; ++i) { o[2 * i] = f2bf(a[i].x); o[2 * i + 1] = f2bf(a[i].y); }
    *(u16x8*)(G + rowbase + 2 * 128 + lane * 8) = o;

    // ext cols: lanes 0..7 write 8 bf16 each -> kk = lane*8+j
    if (lane < 8) {
        int dt[3] = {dt0, dt1, dt2};
        u16x8 e;
#pragma unroll
        for (int j = 0; j < 8; ++j) {
            int kk = lane * 8 + j;
            float v;
            if (kk < 3)       v = (float)dt[kk];
            else if (kk < 19) v = S[((size_t)(0 * NNODES + n)) * 16 + (kk - 3)];
            else if (kk < 35) v = S[((size_t)(1 * NNODES + n)) * 16 + (kk - 19)];
            else              v = 0.f;
            e[j] = f2bf(v);
        }
        *(u16x8*)(G + rowbase + 384 + lane * 8) = e;
    }
}

// ---------- K6: bf16 MFMA GEMM [64x448]@[448x128] + residual + ReLU + LN ----------
// (r6 shape: 64-row M-tile, 4 blocks/CU, 1250 blocks)
__global__ __launch_bounds__(256) void k_gemm_ln(const unsigned short* __restrict__ G,   // [BROWS][448]
                                                 const unsigned short* __restrict__ Wt,  // [128][448]
                                                 unsigned short* HB,
                                                 const float* __restrict__ lng,
                                                 const float* __restrict__ lnb,
                                                 float* __restrict__ out, int write_f32) {
    __shared__ __align__(16) unsigned short Gs[64][LDW];
    __shared__ __align__(16) unsigned short Ws[128][LDW];
    int t = threadIdx.x;
    int m0 = blockIdx.x * 64;
    int w = t >> 6, lane = t & 63;
    int q = lane >> 4, lm = lane & 15;

    f32x4 acc[8];
#pragma unroll
    for (int ct = 0; ct < 8; ++ct) acc[ct] = (f32x4){0.f, 0.f, 0.f, 0.f};

    for (int kc = 0; kc < 7; ++kc) {
        // stage G chunk: 64 rows x 64 k (512 uint4)
#pragma unroll
        for (int i = 0; i < 2; ++i) {
            int lin = t + 256 * i;
            int row = lin >> 3, seg = lin & 7;
            *(uint4*)&Gs[row][seg * 8] =
                *(const uint4*)(G + (size_t)(m0 + row) * KE + kc * 64 + seg * 8);
        }
        // stage Wt chunk: 128 rows x 64 k (1024 uint4)
#pragma unroll
        for (int i = 0; i < 4; ++i) {
            int lin = t + 256 * i;
            int row = lin >> 3, seg = lin & 7;
            *(uint4*)&Ws[row][seg * 8] =
                *(const uint4*)(Wt + (size_t)row * KE + kc * 64 + seg * 8);
        }
        __syncthreads();
#pragma unroll
        for (int kt = 0; kt < 2; ++kt) {
            bf16x8 a = *(const bf16x8*)&Gs[w * 16 + lm][kt * 32 + q * 8];
#pragma unroll
            for (int ct = 0; ct < 8; ++ct) {
                bf16x8 bf = *(const bf16x8*)&Ws[ct * 16 + lm][kt * 32 + q * 8];
                acc[ct] = __builtin_amdgcn_mfma_f32_16x16x32_bf16(a, bf, acc[ct], 0, 0, 0);
            }
        }
        __syncthreads();
    }

    float gc[8], bc[8];
#pragma unroll
    for (int ct = 0; ct < 8; ++ct) {
        int col = ct * 16 + lm;
        gc[ct] = lng[col]; bc[ct] = lnb[col];
    }
#pragma unroll
    for (int reg = 0; reg < 4; ++reg) {
        size_t row = (size_t)m0 + w * 16 + q * 4 + reg;
        float xv[8];
        float s1 = 0.f, s2 = 0.f;
#pragma unroll
        for (int ct = 0; ct < 8; ++ct) {
            int col = ct * 16 + lm;
            float h = bf2f(HB[row * DM + col]);
            float v = h + fmaxf(acc[ct][reg], 0.f);
            xv[ct] = v; s1 += v; s2 += v * v;
        }
#pragma unroll
        for (int m = 1; m <= 8; m <<= 1) {
            s1 += __shfl_xor(s1, m, 64);
            s2 += __shfl_xor(s2, m, 64);
        }
        float mu  = s1 * (1.f / 128.f);
        float var = s2 * (1.f / 128.f) - mu * mu;
        float inv = rsqrtf(var + LN_EPS);
        if (write_f32) {
#pragma unroll
            for (int ct = 0; ct < 8; ++ct) {
                int col = ct * 16 + lm;
                out[row * DM + col] = (xv[ct] - mu) * inv * gc[ct] + bc[ct];
            }
        } else {
#pragma unroll
            for (int ct = 0; ct < 8; ++ct) {
                int col = ct * 16 + lm;
                HB[row * DM + col] = f2bf((xv[ct] - mu) * inv * gc[ct] + bc[ct]);
            }
        }
    }
}

extern "C" void kernel_launch(void* const* d_in, const int* in_sizes, int n_in,
                              void* d_out, int out_size, void* d_ws, size_t ws_size,
                              hipStream_t stream) {
    const float* node_feat = (const float*)d_in[0];
    const float* in_W   = (const float*)d_in[1];
    const float* in_b   = (const float*)d_in[2];
    const float* node_W = (const float*)d_in[3];   // [2][3][128][128]
    const float* node_b = (const float*)d_in[4];   // [2][3][128]
    const float* edge_W = (const float*)d_in[5];   // [2][2][16][128]
    const float* edge_b = (const float*)d_in[6];   // [2][2][128]
    const float* ln_g   = (const float*)d_in[7];   // [2][128]
    const float* ln_b   = (const float*)d_in[8];   // [2][128]
    const float* ea0    = (const float*)d_in[9];
    const float* ea1    = (const float*)d_in[10];
    const int*   ei0    = (const int*)d_in[11];
    const int*   ei1    = (const int*)d_in[12];
    const int*   ei2    = (const int*)d_in[13];
    float* out = (float*)d_out;

    char* ws = (char*)d_ws;
    size_t off = 0;
    auto alloc = [&](size_t bytes) -> void* {
        void* p = ws + off;
        off = (off + bytes + 255) & ~(size_t)255;
        return p;
    };
    unsigned short* HB     = (unsigned short*)alloc((size_t)BROWS * DM * 2);   // 20.5 MB
    unsigned short* G      = (unsigned short*)alloc((size_t)BROWS * KE * 2);   // 71.7 MB
    int*            cursor = (int*)alloc((size_t)3 * NNODES * 4);              // zeroed
    float*          S      = (float*)alloc((size_t)2 * NNODES * 16 * 4);
    int*            srcs   = (int*)alloc((size_t)3 * NNODES * CAP * 4);        // 15.4 MB
    int*            eids   = (int*)alloc((size_t)2 * NNODES * CAP * 4);        // 10.2 MB
    unsigned short* Wt     = (unsigned short*)alloc((size_t)2 * 128 * KE * 2);
    unsigned short* Wp     = (unsigned short*)alloc((size_t)128 * 64 * 2);

    hipMemsetAsync(cursor, 0, (size_t)3 * NNODES * 4, stream);

    k_scatter<<<(3 * NE + 255) / 256, 256, 0, stream>>>(ei0, ei1, ei2, cursor, srcs, eids);
    k_sgather<<<(2 * NNODES) / 4, 256, 0, stream>>>(cursor, eids, ea0, ea1, S);
    k_wprep<<<480, 256, 0, stream>>>(node_W, node_b, edge_W, edge_b, in_W, Wt, Wp);
    k_proj<<<BROWS / 64, 256, 0, stream>>>(node_feat, Wp, in_b, HB);

    for (int l = 0; l < 2; ++l) {
        k_spmm<<<5000, 256, 0, stream>>>(HB, cursor, srcs, S, G);
        k_gemm_ln<<<BROWS / 64, 256, 0, stream>>>(G, Wt + (size_t)l * 128 * KE, HB,
                                                  ln_g + (size_t)l * DM, ln_b + (size_t)l * DM,
                                                  out, l == 1);
    }
}